// Round 2
// baseline (24785.399 us; speedup 1.0000x reference)
//
#include <hip/hip_runtime.h>
#include <hip/hip_bf16.h>
#include <math.h>

#define NS 256
#define T_LEN 8192
#define NF 32000

// Kernel 1: gather scaled emissions SE[t][j] = E[j, obs[t]] * 2^15 (exact scale)
__global__ void gather_emis(const float* __restrict__ E, const int* __restrict__ obs,
                            float* __restrict__ SE) {
    int t = blockIdx.x;
    int j = threadIdx.x;
    int o = obs[t];
    SE[t * NS + j] = E[(size_t)j * NF + o] * 32768.0f;
}

// Kernel 2: sequential forward recursion, single workgroup, A column in registers.
__global__ __launch_bounds__(NS, 1)
void hmm_forward(const float* __restrict__ start,
                 const float* __restrict__ A,
                 const float* __restrict__ E,
                 const int* __restrict__ obs,
                 const float* __restrict__ SE,
                 float* __restrict__ out,
                 int use_se) {
    __shared__ float xbuf[2][NS];
    __shared__ float red[4];
    const int j = threadIdx.x;

    // Load my column of the transition matrix into registers (coalesced per row).
    float a[NS];
#pragma unroll
    for (int i = 0; i < NS; ++i) a[i] = A[i * NS + j];

    const float LN2 = 0.69314718055994530942f;
    float Eacc = 0.0f;  // accumulated power-of-2 renorm exponent

    // t = 0:  z0 = start[j] * E[j, obs0] * 2^15
    int o0 = obs[0];
    float z = start[j] * E[(size_t)j * NF + o0] * 32768.0f;
    out[(size_t)j * T_LEN + 0] = LN2 * (__log2f(z) - 15.0f);
    xbuf[0][j] = z;
    __syncthreads();

    float se_cur = use_se ? SE[1 * NS + j]
                          : E[(size_t)j * NF + obs[1]] * 32768.0f;

    for (int t = 1; t < T_LEN; ++t) {
        // Prefetch next step's emission while the dot product runs.
        float se_nxt = 0.0f;
        if (t + 1 < T_LEN)
            se_nxt = use_se ? SE[(t + 1) * NS + j]
                            : E[(size_t)j * NF + obs[t + 1]] * 32768.0f;

        const float* rd = xbuf[(t - 1) & 1];
        const float4* x4 = (const float4*)rd;  // broadcast LDS reads
        float y0 = 0.f, y1 = 0.f, y2 = 0.f, y3 = 0.f;
#pragma unroll
        for (int i = 0; i < NS / 4; ++i) {
            float4 xv = x4[i];
            y0 = fmaf(xv.x, a[4 * i + 0], y0);
            y1 = fmaf(xv.y, a[4 * i + 1], y1);
            y2 = fmaf(xv.z, a[4 * i + 2], y2);
            y3 = fmaf(xv.w, a[4 * i + 3], y3);
        }
        float y = (y0 + y1) + (y2 + y3);
        y *= se_cur;
        se_cur = se_nxt;

        // true alpha_t = y * 2^Eacc * 2^(-15*(t+1))
        out[(size_t)j * T_LEN + t] =
            LN2 * (__log2f(y) + Eacc - 15.0f * (float)(t + 1));

        float* wr = xbuf[t & 1];
        wr[j] = y;
        __syncthreads();

        // Exact power-of-2 renormalization every 1024 steps (drift ~ +24 e-folds).
        if ((t & 1023) == 1023) {
            float v = wr[j];
#pragma unroll
            for (int d = 1; d < 64; d <<= 1)
                v = fmaxf(v, __shfl_xor(v, d, 64));
            if ((j & 63) == 0) red[j >> 6] = v;
            __syncthreads();
            float m = fmaxf(fmaxf(red[0], red[1]), fmaxf(red[2], red[3]));
            int k = ilogbf(m);
            wr[j] = ldexpf(wr[j], -k);
            Eacc += (float)k;
            __syncthreads();
        }
    }
}

extern "C" void kernel_launch(void* const* d_in, const int* in_sizes, int n_in,
                              void* d_out, int out_size, void* d_ws, size_t ws_size,
                              hipStream_t stream) {
    const float* start = (const float*)d_in[0];
    const float* A     = (const float*)d_in[1];
    const float* E     = (const float*)d_in[2];
    const int*   obs   = (const int*)d_in[3];
    float* out = (float*)d_out;
    float* SE  = (float*)d_ws;

    const size_t se_bytes = (size_t)T_LEN * NS * sizeof(float);
    int use_se = (ws_size >= se_bytes) ? 1 : 0;

    if (use_se) gather_emis<<<T_LEN, NS, 0, stream>>>(E, obs, SE);
    hmm_forward<<<1, NS, 0, stream>>>(start, A, E, obs, SE, out, use_se);
}

// Round 3
// 131.187 us; speedup vs baseline: 188.9325x; 188.9325x over previous
//
#include <hip/hip_runtime.h>
#include <hip/hip_bf16.h>
#include <math.h>

#define NS 256
#define T_LEN 8192
#define NF 32000
#define L_CHUNK 32
#define B_BURN 32
#define C_CHUNKS 256   // T_LEN / L_CHUNK
#define SCALE 32768.0f

// ---------------- chunked chains: 256 blocks x 1024 threads ----------------
// Block c computes alpha-direction vectors for t in [c*L, c*L+L) after a
// B-step burn-in from a uniform vector (chunk 0 starts exact, no burn-in).
// Thread (q=tid>>8, j=tid&255) holds A[64q..64q+63, j] in 64 registers.
__global__ __launch_bounds__(1024)
void hmm_chunks(const float* __restrict__ start,
                const float* __restrict__ A,
                const float* __restrict__ E,
                const int* __restrict__ obs,
                float* __restrict__ zbuf,   // [T][NS] scaled alpha vectors
                float* __restrict__ Pb,     // [C] chunk-end stitch values
                float* __restrict__ Qb)     // [C] burn-in-end stitch values
{
    const int c   = blockIdx.x;
    const int tid = threadIdx.x;
    const int j   = tid & (NS - 1);
    const int q   = tid >> 8;          // 0..3

    __shared__ float xcur[NS];
    __shared__ float part[4][NS];

    // my quarter-column of A (64 VGPRs; coalesced loads over j)
    float a[64];
#pragma unroll
    for (int i = 0; i < 64; ++i)
        a[i] = A[(size_t)(64 * q + i) * NS + j];

    int ts, te;
    float se_cur = 0.f, se_nxt = 0.f;
    if (c == 0) {
        ts = 1; te = L_CHUNK - 1;
        if (q == 0) {
            float se0 = E[(size_t)j * NF + obs[0]] * SCALE;
            float y0  = start[j] * se0;          // z_0 = alpha_0 * 2^15
            zbuf[0 * NS + j] = y0;
            xcur[j] = y0;
            se_cur = E[(size_t)j * NF + obs[1]] * SCALE;
            se_nxt = E[(size_t)j * NF + obs[2]] * SCALE;
        }
    } else {
        ts = c * L_CHUNK - B_BURN;
        te = c * L_CHUNK + L_CHUNK - 1;
        if (q == 0) {
            xcur[j] = 1.0f;                      // uniform start, burned in
            se_cur = E[(size_t)j * NF + obs[ts]] * SCALE;
            se_nxt = E[(size_t)j * NF + obs[ts + 1]] * SCALE;
        }
    }
    __syncthreads();

    const int tq = c * L_CHUNK - 1;   // stitch point vs previous chunk (c>0)
    const int tp = te;                // stitch point for next chunk

    for (int t = ts; t <= te; ++t) {
        // partial matvec: p_{q,j} = sum_{i in quarter q} x_i * A[i][j]
        const float4* x4 = (const float4*)xcur;   // broadcast LDS reads
        float y0 = 0.f, y1 = 0.f, y2 = 0.f, y3 = 0.f;
#pragma unroll
        for (int i = 0; i < 16; ++i) {
            float4 xv = x4[16 * q + i];
            y0 = fmaf(xv.x, a[4 * i + 0], y0);
            y1 = fmaf(xv.y, a[4 * i + 1], y1);
            y2 = fmaf(xv.z, a[4 * i + 2], y2);
            y3 = fmaf(xv.w, a[4 * i + 3], y3);
        }
        part[q][j] = (y0 + y1) + (y2 + y3);
        __syncthreads();

        if (q == 0) {
            float y = (part[0][j] + part[1][j]) + (part[2][j] + part[3][j]);
            y *= se_cur;
            if (t >= c * L_CHUNK) zbuf[(size_t)t * NS + j] = y;  // body only
            xcur[j] = y;
            // rotate emission pipeline; prefetch t+2 (clamped)
            se_cur = se_nxt;
            int tt = t + 2; if (tt > te) tt = te;
            se_nxt = E[(size_t)j * NF + obs[tt]] * SCALE;
        }
        __syncthreads();

        if (t == tq || t == tp) {
            // V(t) = log2(sum_j z_t[j]) - 15*(t+1); same quantity measured by
            // adjacent chunks at the same t differs by the chunks' offsets.
            if (tid < 64) {
                float s = (xcur[tid] + xcur[tid + 64]) +
                          (xcur[tid + 128] + xcur[tid + 192]);
#pragma unroll
                for (int d = 1; d < 64; d <<= 1) s += __shfl_xor(s, d, 64);
                if (tid == 0) {
                    float v = log2f(s) - 15.0f * (float)(t + 1);
                    if (t == tq) Qb[c] = v; else Pb[c] = v;
                }
            }
        }
    }
}

// ---------------- stitch: serial f64 scan over 256 chunk offsets ----------
__global__ void hmm_stitch(const float* __restrict__ Pb,
                           const float* __restrict__ Qb,
                           float* __restrict__ Dfull)   // [T]
{
    __shared__ double Dd[C_CHUNKS];
    int tid = threadIdx.x;
    if (tid == 0) {
        double d = 0.0;
        Dd[0] = 0.0;
        for (int cc = 1; cc < C_CHUNKS; ++cc) {
            d += (double)Pb[cc - 1] - (double)Qb[cc];
            Dd[cc] = d;
        }
    }
    __syncthreads();
    for (int t = tid; t < T_LEN; t += blockDim.x)
        Dfull[t] = (float)(Dd[t / L_CHUNK] - 15.0 * (double)(t + 1));
}

// ---------------- finalize: log + 64x64 tiled transpose -------------------
__global__ __launch_bounds__(256)
void hmm_finalize(const float* __restrict__ zbuf,
                  const float* __restrict__ Dfull,
                  float* __restrict__ out)
{
    __shared__ float tile[64][65];
    const int t0   = blockIdx.x * 64;
    const int j0   = blockIdx.y * 64;
    const int lane = threadIdx.x & 63;
    const int row4 = threadIdx.x >> 6;   // 0..3
    const float LN2 = 0.69314718055994530942f;

#pragma unroll
    for (int r = 0; r < 16; ++r) {
        int trow = r * 4 + row4;
        int t = t0 + trow;
        float z = zbuf[(size_t)t * NS + j0 + lane];
        tile[trow][lane] = __log2f(z) + Dfull[t];
    }
    __syncthreads();
#pragma unroll
    for (int r = 0; r < 16; ++r) {
        int jrow = r * 4 + row4;
        out[(size_t)(j0 + jrow) * T_LEN + t0 + lane] = LN2 * tile[lane][jrow];
    }
}

// ---------------- fallback: single-workgroup sequential (R2) --------------
__global__ __launch_bounds__(NS, 1)
void hmm_forward_seq(const float* __restrict__ start,
                     const float* __restrict__ A,
                     const float* __restrict__ E,
                     const int* __restrict__ obs,
                     float* __restrict__ out)
{
    __shared__ float xbuf[2][NS];
    __shared__ float red[4];
    const int j = threadIdx.x;
    float a[NS];
#pragma unroll
    for (int i = 0; i < NS; ++i) a[i] = A[i * NS + j];
    const float LN2 = 0.69314718055994530942f;
    float Eacc = 0.0f;
    float z = start[j] * E[(size_t)j * NF + obs[0]] * SCALE;
    out[(size_t)j * T_LEN + 0] = LN2 * (__log2f(z) - 15.0f);
    xbuf[0][j] = z;
    __syncthreads();
    float se_cur = E[(size_t)j * NF + obs[1]] * SCALE;
    for (int t = 1; t < T_LEN; ++t) {
        float se_nxt = 0.0f;
        if (t + 1 < T_LEN) se_nxt = E[(size_t)j * NF + obs[t + 1]] * SCALE;
        const float4* x4 = (const float4*)xbuf[(t - 1) & 1];
        float y0 = 0.f, y1 = 0.f, y2 = 0.f, y3 = 0.f;
#pragma unroll
        for (int i = 0; i < NS / 4; ++i) {
            float4 xv = x4[i];
            y0 = fmaf(xv.x, a[4 * i + 0], y0);
            y1 = fmaf(xv.y, a[4 * i + 1], y1);
            y2 = fmaf(xv.z, a[4 * i + 2], y2);
            y3 = fmaf(xv.w, a[4 * i + 3], y3);
        }
        float y = ((y0 + y1) + (y2 + y3)) * se_cur;
        se_cur = se_nxt;
        out[(size_t)j * T_LEN + t] =
            LN2 * (__log2f(y) + Eacc - 15.0f * (float)(t + 1));
        float* wr = xbuf[t & 1];
        wr[j] = y;
        __syncthreads();
        if ((t & 1023) == 1023) {
            float v = wr[j];
#pragma unroll
            for (int d = 1; d < 64; d <<= 1) v = fmaxf(v, __shfl_xor(v, d, 64));
            if ((j & 63) == 0) red[j >> 6] = v;
            __syncthreads();
            float m = fmaxf(fmaxf(red[0], red[1]), fmaxf(red[2], red[3]));
            int k = ilogbf(m);
            wr[j] = ldexpf(wr[j], -k);
            Eacc += (float)k;
            __syncthreads();
        }
    }
}

extern "C" void kernel_launch(void* const* d_in, const int* in_sizes, int n_in,
                              void* d_out, int out_size, void* d_ws, size_t ws_size,
                              hipStream_t stream) {
    const float* start = (const float*)d_in[0];
    const float* A     = (const float*)d_in[1];
    const float* E     = (const float*)d_in[2];
    const int*   obs   = (const int*)d_in[3];
    float* out = (float*)d_out;

    float* z     = (float*)d_ws;                 // [T][NS]
    float* Pb    = z + (size_t)T_LEN * NS;       // [C]
    float* Qb    = Pb + C_CHUNKS;                // [C]
    float* Dfull = Qb + C_CHUNKS;                // [T]
    const size_t need = ((size_t)T_LEN * NS + 2 * C_CHUNKS + T_LEN) * sizeof(float);

    if (ws_size >= need) {
        hmm_chunks<<<C_CHUNKS, 1024, 0, stream>>>(start, A, E, obs, z, Pb, Qb);
        hmm_stitch<<<1, 256, 0, stream>>>(Pb, Qb, Dfull);
        hmm_finalize<<<dim3(T_LEN / 64, NS / 64), 256, 0, stream>>>(z, Dfull, out);
    } else {
        hmm_forward_seq<<<1, NS, 0, stream>>>(start, A, E, obs, out);
    }
}

// Round 4
// 128.608 us; speedup vs baseline: 192.7204x; 1.0200x over previous
//
#include <hip/hip_runtime.h>
#include <hip/hip_bf16.h>
#include <math.h>

#define NS 256
#define T_LEN 8192
#define NF 32000
#define L_CHUNK 32
#define B_BURN 32
#define C_CHUNKS 256   // T_LEN / L_CHUNK
#define SCALE 32768.0f

// ---------------- transpose + scale: ET[o][j] = E[j][o] * 2^15 ------------
__global__ __launch_bounds__(256)
void transpose_E(const float* __restrict__ E, float* __restrict__ ET) {
    __shared__ float tile[64][65];
    const int o0 = blockIdx.x * 64;        // 500
    const int j0 = blockIdx.y * 64;        // 4
    const int lane = threadIdx.x & 63;
    const int r4 = threadIdx.x >> 6;       // 0..3
#pragma unroll
    for (int r = 0; r < 16; ++r) {
        int jrow = r * 4 + r4;
        tile[jrow][lane] = E[(size_t)(j0 + jrow) * NF + o0 + lane] * SCALE;
    }
    __syncthreads();
#pragma unroll
    for (int r = 0; r < 16; ++r) {
        int orow = r * 4 + r4;
        ET[(size_t)(o0 + orow) * NS + j0 + lane] = tile[lane][orow];
    }
}

// ---------------- chunked chains: 256 blocks x 1024 threads ----------------
// Thread (q=tid>>8, j=tid&255) holds A[64q..64q+63, j] in 64 VGPRs.
// Matvec: wave reads its x-quarter (1 ds_read_b32), then 64x readlane+FMA.
__global__ __launch_bounds__(1024, 4)
void hmm_chunks(const float* __restrict__ start,
                const float* __restrict__ A,
                const float* __restrict__ E,
                const int* __restrict__ obs,
                const float* __restrict__ ET,
                int use_et,
                float* __restrict__ zbuf,   // [T][NS]
                float* __restrict__ Pb,     // [C]
                float* __restrict__ Qb)     // [C]
{
    const int c    = blockIdx.x;
    const int tid  = threadIdx.x;
    const int j    = tid & (NS - 1);
    const int q    = tid >> 8;             // 0..3 (wave-uniform)
    const int lane = tid & 63;

    __shared__ float xcur[NS];
    __shared__ float part[3][NS];          // partials for q=1..3

    // my quarter-column of A, pinned in VGPRs
    float a[64];
#pragma unroll
    for (int i = 0; i < 64; ++i)
        a[i] = A[(size_t)(64 * q + i) * NS + j];
#pragma unroll
    for (int i = 0; i < 64; ++i)
        asm volatile("" : "+v"(a[i]));

    int ts, te;
    float se_cur = 0.f, se_nxt = 0.f;
    if (c == 0) {
        ts = 1; te = L_CHUNK - 1;
        if (q == 0) {
            float se0 = use_et ? ET[(size_t)obs[0] * NS + j]
                               : E[(size_t)j * NF + obs[0]] * SCALE;
            float y0  = start[j] * se0;
            zbuf[0 * NS + j] = y0;
            xcur[j] = y0;
            se_cur = use_et ? ET[(size_t)obs[1] * NS + j]
                            : E[(size_t)j * NF + obs[1]] * SCALE;
            se_nxt = use_et ? ET[(size_t)obs[2] * NS + j]
                            : E[(size_t)j * NF + obs[2]] * SCALE;
        }
    } else {
        ts = c * L_CHUNK - B_BURN;
        te = c * L_CHUNK + L_CHUNK - 1;
        if (q == 0) {
            xcur[j] = 1.0f;
            se_cur = use_et ? ET[(size_t)obs[ts] * NS + j]
                            : E[(size_t)j * NF + obs[ts]] * SCALE;
            se_nxt = use_et ? ET[(size_t)obs[ts + 1] * NS + j]
                            : E[(size_t)j * NF + obs[ts + 1]] * SCALE;
        }
    }
    __syncthreads();

    const int tq = c * L_CHUNK - 1;
    const int tp = te;

    for (int t = ts; t <= te; ++t) {
        // each wave reads its 64-value x-quarter: one b32, 2-way bank (free)
        float x = xcur[64 * q + lane];
        float a0 = 0.f, a1 = 0.f, a2 = 0.f, a3 = 0.f;
#pragma unroll
        for (int i = 0; i < 64; i += 4) {
            a0 = fmaf(__int_as_float(__builtin_amdgcn_readlane(__float_as_int(x), i + 0)), a[i + 0], a0);
            a1 = fmaf(__int_as_float(__builtin_amdgcn_readlane(__float_as_int(x), i + 1)), a[i + 1], a1);
            a2 = fmaf(__int_as_float(__builtin_amdgcn_readlane(__float_as_int(x), i + 2)), a[i + 2], a2);
            a3 = fmaf(__int_as_float(__builtin_amdgcn_readlane(__float_as_int(x), i + 3)), a[i + 3], a3);
        }
        float p = (a0 + a1) + (a2 + a3);
        if (q) part[q - 1][j] = p;
        __syncthreads();

        if (!q) {
            float y = ((p + part[0][j]) + (part[1][j] + part[2][j])) * se_cur;
            if (t >= c * L_CHUNK) zbuf[(size_t)t * NS + j] = y;
            xcur[j] = y;
            se_cur = se_nxt;
            int tt = t + 2; if (tt > te) tt = te;
            se_nxt = use_et ? ET[(size_t)obs[tt] * NS + j]
                            : E[(size_t)j * NF + obs[tt]] * SCALE;
        }
        __syncthreads();

        if (t == tq || t == tp) {
            if (tid < 64) {
                float s = (xcur[tid] + xcur[tid + 64]) +
                          (xcur[tid + 128] + xcur[tid + 192]);
#pragma unroll
                for (int d = 1; d < 64; d <<= 1) s += __shfl_xor(s, d, 64);
                if (tid == 0) {
                    float v = log2f(s) - 15.0f * (float)(t + 1);
                    if (t == tq) Qb[c] = v; else Pb[c] = v;
                }
            }
        }
    }
}

// ---------------- stitch: serial f64 scan over 256 chunk offsets ----------
__global__ void hmm_stitch(const float* __restrict__ Pb,
                           const float* __restrict__ Qb,
                           float* __restrict__ Dfull)
{
    __shared__ double Dd[C_CHUNKS];
    int tid = threadIdx.x;
    if (tid == 0) {
        double d = 0.0;
        Dd[0] = 0.0;
        for (int cc = 1; cc < C_CHUNKS; ++cc) {
            d += (double)Pb[cc - 1] - (double)Qb[cc];
            Dd[cc] = d;
        }
    }
    __syncthreads();
    for (int t = tid; t < T_LEN; t += blockDim.x)
        Dfull[t] = (float)(Dd[t / L_CHUNK] - 15.0 * (double)(t + 1));
}

// ---------------- finalize: log + 64x64 tiled transpose -------------------
__global__ __launch_bounds__(256)
void hmm_finalize(const float* __restrict__ zbuf,
                  const float* __restrict__ Dfull,
                  float* __restrict__ out)
{
    __shared__ float tile[64][65];
    const int t0   = blockIdx.x * 64;
    const int j0   = blockIdx.y * 64;
    const int lane = threadIdx.x & 63;
    const int row4 = threadIdx.x >> 6;
    const float LN2 = 0.69314718055994530942f;

#pragma unroll
    for (int r = 0; r < 16; ++r) {
        int trow = r * 4 + row4;
        int t = t0 + trow;
        float z = zbuf[(size_t)t * NS + j0 + lane];
        tile[trow][lane] = __log2f(z) + Dfull[t];
    }
    __syncthreads();
#pragma unroll
    for (int r = 0; r < 16; ++r) {
        int jrow = r * 4 + row4;
        out[(size_t)(j0 + jrow) * T_LEN + t0 + lane] = LN2 * tile[lane][jrow];
    }
}

// ---------------- fallback: single-workgroup sequential -------------------
__global__ __launch_bounds__(NS, 1)
void hmm_forward_seq(const float* __restrict__ start,
                     const float* __restrict__ A,
                     const float* __restrict__ E,
                     const int* __restrict__ obs,
                     float* __restrict__ out)
{
    __shared__ float xbuf[2][NS];
    __shared__ float red[4];
    const int j = threadIdx.x;
    float a[NS];
#pragma unroll
    for (int i = 0; i < NS; ++i) a[i] = A[i * NS + j];
    const float LN2 = 0.69314718055994530942f;
    float Eacc = 0.0f;
    float z = start[j] * E[(size_t)j * NF + obs[0]] * SCALE;
    out[(size_t)j * T_LEN + 0] = LN2 * (__log2f(z) - 15.0f);
    xbuf[0][j] = z;
    __syncthreads();
    float se_cur = E[(size_t)j * NF + obs[1]] * SCALE;
    for (int t = 1; t < T_LEN; ++t) {
        float se_nxt = 0.0f;
        if (t + 1 < T_LEN) se_nxt = E[(size_t)j * NF + obs[t + 1]] * SCALE;
        const float4* x4 = (const float4*)xbuf[(t - 1) & 1];
        float y0 = 0.f, y1 = 0.f, y2 = 0.f, y3 = 0.f;
#pragma unroll
        for (int i = 0; i < NS / 4; ++i) {
            float4 xv = x4[i];
            y0 = fmaf(xv.x, a[4 * i + 0], y0);
            y1 = fmaf(xv.y, a[4 * i + 1], y1);
            y2 = fmaf(xv.z, a[4 * i + 2], y2);
            y3 = fmaf(xv.w, a[4 * i + 3], y3);
        }
        float y = ((y0 + y1) + (y2 + y3)) * se_cur;
        se_cur = se_nxt;
        out[(size_t)j * T_LEN + t] =
            LN2 * (__log2f(y) + Eacc - 15.0f * (float)(t + 1));
        float* wr = xbuf[t & 1];
        wr[j] = y;
        __syncthreads();
        if ((t & 1023) == 1023) {
            float v = wr[j];
#pragma unroll
            for (int d = 1; d < 64; d <<= 1) v = fmaxf(v, __shfl_xor(v, d, 64));
            if ((j & 63) == 0) red[j >> 6] = v;
            __syncthreads();
            float m = fmaxf(fmaxf(red[0], red[1]), fmaxf(red[2], red[3]));
            int k = ilogbf(m);
            wr[j] = ldexpf(wr[j], -k);
            Eacc += (float)k;
            __syncthreads();
        }
    }
}

extern "C" void kernel_launch(void* const* d_in, const int* in_sizes, int n_in,
                              void* d_out, int out_size, void* d_ws, size_t ws_size,
                              hipStream_t stream) {
    const float* start = (const float*)d_in[0];
    const float* A     = (const float*)d_in[1];
    const float* E     = (const float*)d_in[2];
    const int*   obs   = (const int*)d_in[3];
    float* out = (float*)d_out;

    float* z     = (float*)d_ws;                       // [T][NS]
    float* Pb    = z + (size_t)T_LEN * NS;             // [C]
    float* Qb    = Pb + C_CHUNKS;                      // [C]
    float* Dfull = Qb + C_CHUNKS;                      // [T]
    float* ET    = Dfull + T_LEN;                      // [NF][NS]

    const size_t need_base = ((size_t)T_LEN * NS + 2 * C_CHUNKS + T_LEN) * sizeof(float);
    const size_t need_full = need_base + (size_t)NF * NS * sizeof(float);

    if (ws_size >= need_full) {
        transpose_E<<<dim3(NF / 64, NS / 64), 256, 0, stream>>>(E, ET);
        hmm_chunks<<<C_CHUNKS, 1024, 0, stream>>>(start, A, E, obs, ET, 1, z, Pb, Qb);
        hmm_stitch<<<1, 256, 0, stream>>>(Pb, Qb, Dfull);
        hmm_finalize<<<dim3(T_LEN / 64, NS / 64), 256, 0, stream>>>(z, Dfull, out);
    } else if (ws_size >= need_base) {
        hmm_chunks<<<C_CHUNKS, 1024, 0, stream>>>(start, A, E, obs, (const float*)0, 0, z, Pb, Qb);
        hmm_stitch<<<1, 256, 0, stream>>>(Pb, Qb, Dfull);
        hmm_finalize<<<dim3(T_LEN / 64, NS / 64), 256, 0, stream>>>(z, Dfull, out);
    } else {
        hmm_forward_seq<<<1, NS, 0, stream>>>(start, A, E, obs, out);
    }
}

// Round 5
// 96.850 us; speedup vs baseline: 255.9161x; 1.3279x over previous
//
#include <hip/hip_runtime.h>
#include <hip/hip_bf16.h>
#include <math.h>

#define NS 256
#define T_LEN 8192
#define NF 32000
#define L_CH 16
#define B_BN 16
#define S_TOT 32          // B_BN + L_CH
#define C_CH 512          // T_LEN / L_CH
#define G_CH 16           // chains per block
#define NBLK 32           // C_CH / G_CH
#define SCALE 32768.0f

typedef short short8 __attribute__((ext_vector_type(8)));
typedef float f32x4 __attribute__((ext_vector_type(4)));

__device__ __forceinline__ short f2bs(float f) {
    union { __bf16 b; short s; } u; u.b = (__bf16)f; return u.s;
}
__device__ __forceinline__ float bs2f(short s) {
    union { short s; __bf16 b; } u; u.s = s; return (float)u.b;
}

// ---- transpose + scale to bf16: ETb[o][j] = bf16(E[j][o] * 2^15) ----------
__global__ __launch_bounds__(256)
void transpose_E(const float* __restrict__ E, short* __restrict__ ETb) {
    __shared__ float tile[64][65];
    const int o0 = blockIdx.x * 64;
    const int j0 = blockIdx.y * 64;
    const int lane = threadIdx.x & 63;
    const int r4 = threadIdx.x >> 6;
#pragma unroll
    for (int r = 0; r < 16; ++r) {
        int jrow = r * 4 + r4;
        tile[jrow][lane] = E[(size_t)(j0 + jrow) * NF + o0 + lane] * SCALE;
    }
    __syncthreads();
#pragma unroll
    for (int r = 0; r < 16; ++r) {
        int orow = r * 4 + r4;
        ETb[(size_t)(o0 + orow) * NS + j0 + lane] = f2bs(tile[lane][orow]);
    }
}

// ---- pre-swizzle A into MFMA B-fragment order (bf16) ----------------------
// frag (ntile, kk, lane, e) = A[kk*32 + (lane>>4)*8 + e][ntile*16 + (lane&15)]
__global__ __launch_bounds__(64)
void prep_A(const float* __restrict__ A, short* __restrict__ Aswz) {
    const int ntg  = blockIdx.x >> 3;   // 0..15
    const int kk   = blockIdx.x & 7;    // 0..7
    const int lane = threadIdx.x;       // 0..63
    const int col  = ntg * 16 + (lane & 15);
    const int krow = kk * 32 + (lane >> 4) * 8;
    short8 v;
#pragma unroll
    for (int e = 0; e < 8; ++e)
        v[e] = f2bs(A[(size_t)(krow + e) * NS + col]);
    *(short8*)&Aswz[((size_t)blockIdx.x * 64 + lane) * 8] = v;
}

// ---- chained MFMA steps: 32 blocks x 256 threads, 16 chains/block ---------
__global__ __launch_bounds__(256, 1)
void hmm_chains(const float* __restrict__ start,
                const int* __restrict__ obs,
                const short* __restrict__ ETb,
                const short* __restrict__ Aswz,
                float* __restrict__ zbuf,
                float* __restrict__ Pb, float* __restrict__ Qb)
{
    const int bid  = blockIdx.x;
    const int tid  = threadIdx.x;
    const int w    = tid >> 6;          // wave 0..3  (owns N-tiles 4w..4w+3)
    const int lane = tid & 63;
    const int cj   = lane & 15;         // n-col within tile; also m-row for ax
    const int rq   = lane >> 4;         // lane quarter
    const int base = 256 * bid - 16;    // t = base + 16*g + s

    __shared__ short xb[2][G_CH][264];  // bf16 x, padded row (528 B)

    // B-fragments of A: 32 frags x 8 bf16 = 128 VGPRs, loaded once
    short8 bfr[4][8];
    const short8* Av = (const short8*)Aswz;
#pragma unroll
    for (int nt = 0; nt < 4; ++nt)
#pragma unroll
        for (int kk = 0; kk < 8; ++kk)
            bfr[nt][kk] = Av[((w * 4 + nt) * 8 + kk) * 64 + lane];

    // init x = 1 (burn-in start)
    for (int idx = tid; idx < G_CH * 264; idx += 256)
        ((short*)xb[0])[idx] = f2bs(1.0f);

    // obs prologue for s = 1
    int ocur[4];
#pragma unroll
    for (int r = 0; r < 4; ++r) {
        int g = rq * 4 + r;
        int t = base + 16 * g + 1;
        t = t < 0 ? 0 : t;
        ocur[r] = obs[t];
    }

    for (int s = 1; s < S_TOT; ++s) {
        __syncthreads();
        const int rb = (s - 1) & 1, wb = s & 1;

        if (s == B_BN) {   // Q stitch: state after step B-1, from xb[rb]
            int g = tid >> 4, part = tid & 15;
            float ss = 0.f;
            const short* row = &xb[rb][g][part * 16];
#pragma unroll
            for (int i = 0; i < 16; ++i) ss += bs2f(row[i]);
#pragma unroll
            for (int m = 1; m < 16; m <<= 1) ss += __shfl_xor(ss, m, 16);
            if (part == 0) {
                int t1 = base + 16 * g + 16;    // t+1, t = base+16g+15
                Qb[bid * G_CH + g] = log2f(ss) - 15.0f * (float)t1;
            }
        }

        // obs prefetch for s+1
        int onxt[4];
#pragma unroll
        for (int r = 0; r < 4; ++r) {
            int g = rq * 4 + r;
            int t = base + 16 * g + s + 1;
            t = t < 0 ? 0 : (t > T_LEN - 1 ? T_LEN - 1 : t);
            onxt[r] = obs[t];
        }

        // emission values for this step (16 scalars/lane, L2-resident ETb)
        float ev[4][4];
#pragma unroll
        for (int nt = 0; nt < 4; ++nt) {
            int col = (w * 4 + nt) * 16 + cj;
#pragma unroll
            for (int r = 0; r < 4; ++r)
                ev[nt][r] = bs2f(ETb[(size_t)ocur[r] * NS + col]);
        }

        // x A-frags: lane holds x[m=cj][k = kk*32 + rq*8 + 0..7]
        short8 ax[8];
#pragma unroll
        for (int kk = 0; kk < 8; ++kk)
            ax[kk] = *(const short8*)&xb[rb][cj][kk * 32 + rq * 8];

        // y[16 x 256] = x[16 x 256] * A[256 x 256]
        f32x4 acc[4];
#pragma unroll
        for (int nt = 0; nt < 4; ++nt) {
            acc[nt] = (f32x4){0.f, 0.f, 0.f, 0.f};
#pragma unroll
            for (int kk = 0; kk < 8; ++kk)
                acc[nt] = __builtin_amdgcn_mfma_f32_16x16x32_bf16(
                    ax[kk], bfr[nt][kk], acc[nt], 0, 0, 0);
        }

        // apply emissions; write next x (bf16) + zbuf (f32, body steps)
        const bool body = (s >= B_BN);
#pragma unroll
        for (int nt = 0; nt < 4; ++nt) {
            int col = (w * 4 + nt) * 16 + cj;
#pragma unroll
            for (int r = 0; r < 4; ++r) {
                int g = rq * 4 + r;                  // C-frag row = chain
                float y = acc[nt][r] * ev[nt][r];
                bool skip = (bid == 0) && (s == B_BN) && (g == 0);
                if (!skip) {
                    xb[wb][g][col] = f2bs(y);
                    if (body) {
                        int tg = base + 16 * g + s;
                        zbuf[(size_t)tg * NS + col] = y;
                    }
                }
            }
        }

        // chain-0 exact re-init at s == B (t = 0): x0 = start * e0 * 2^15
        if (bid == 0 && s == B_BN) {
            int o0 = obs[0];
            float y0 = start[tid] * bs2f(ETb[(size_t)o0 * NS + tid]);
            xb[wb][0][tid] = f2bs(y0);
            zbuf[tid] = y0;
        }

#pragma unroll
        for (int r = 0; r < 4; ++r) ocur[r] = onxt[r];
    }

    // P stitch: chunk-end state, from xb[(S_TOT-1)&1] = xb[1]
    __syncthreads();
    {
        int g = tid >> 4, part = tid & 15;
        float ss = 0.f;
        const short* row = &xb[1][g][part * 16];
#pragma unroll
        for (int i = 0; i < 16; ++i) ss += bs2f(row[i]);
#pragma unroll
        for (int m = 1; m < 16; m <<= 1) ss += __shfl_xor(ss, m, 16);
        if (part == 0) {
            int t1 = base + 16 * g + 32;   // t+1, t = base+16g+31
            Pb[bid * G_CH + g] = log2f(ss) - 15.0f * (float)t1;
        }
    }
}

// ---- stitch: serial f64 scan over 512 chunk offsets -----------------------
__global__ void hmm_stitch(const float* __restrict__ Pb,
                           const float* __restrict__ Qb,
                           float* __restrict__ Dfull)
{
    __shared__ double Dd[C_CH];
    int tid = threadIdx.x;
    if (tid == 0) {
        double d = 0.0;
        Dd[0] = 0.0;
        for (int cc = 1; cc < C_CH; ++cc) {
            d += (double)Pb[cc - 1] - (double)Qb[cc];
            Dd[cc] = d;
        }
    }
    __syncthreads();
    for (int t = tid; t < T_LEN; t += blockDim.x)
        Dfull[t] = (float)(Dd[t / L_CH] - 15.0 * (double)(t + 1));
}

// ---- finalize: log2 + offset, 64x64 tiled transpose to [NS][T] ------------
__global__ __launch_bounds__(256)
void hmm_finalize(const float* __restrict__ zbuf,
                  const float* __restrict__ Dfull,
                  float* __restrict__ out)
{
    __shared__ float tile[64][65];
    const int t0   = blockIdx.x * 64;
    const int j0   = blockIdx.y * 64;
    const int lane = threadIdx.x & 63;
    const int row4 = threadIdx.x >> 6;
    const float LN2 = 0.69314718055994530942f;

#pragma unroll
    for (int r = 0; r < 16; ++r) {
        int trow = r * 4 + row4;
        int t = t0 + trow;
        float z = zbuf[(size_t)t * NS + j0 + lane];
        tile[trow][lane] = __log2f(z) + Dfull[t];
    }
    __syncthreads();
#pragma unroll
    for (int r = 0; r < 16; ++r) {
        int jrow = r * 4 + row4;
        out[(size_t)(j0 + jrow) * T_LEN + t0 + lane] = LN2 * tile[lane][jrow];
    }
}

// ---- fallback: single-workgroup sequential --------------------------------
__global__ __launch_bounds__(NS, 1)
void hmm_forward_seq(const float* __restrict__ start,
                     const float* __restrict__ A,
                     const float* __restrict__ E,
                     const int* __restrict__ obs,
                     float* __restrict__ out)
{
    __shared__ float xbuf[2][NS];
    __shared__ float red[4];
    const int j = threadIdx.x;
    float a[NS];
#pragma unroll
    for (int i = 0; i < NS; ++i) a[i] = A[i * NS + j];
    const float LN2 = 0.69314718055994530942f;
    float Eacc = 0.0f;
    float z = start[j] * E[(size_t)j * NF + obs[0]] * SCALE;
    out[(size_t)j * T_LEN + 0] = LN2 * (__log2f(z) - 15.0f);
    xbuf[0][j] = z;
    __syncthreads();
    float se_cur = E[(size_t)j * NF + obs[1]] * SCALE;
    for (int t = 1; t < T_LEN; ++t) {
        float se_nxt = 0.0f;
        if (t + 1 < T_LEN) se_nxt = E[(size_t)j * NF + obs[t + 1]] * SCALE;
        const float4* x4 = (const float4*)xbuf[(t - 1) & 1];
        float y0 = 0.f, y1 = 0.f, y2 = 0.f, y3 = 0.f;
#pragma unroll
        for (int i = 0; i < NS / 4; ++i) {
            float4 xv = x4[i];
            y0 = fmaf(xv.x, a[4 * i + 0], y0);
            y1 = fmaf(xv.y, a[4 * i + 1], y1);
            y2 = fmaf(xv.z, a[4 * i + 2], y2);
            y3 = fmaf(xv.w, a[4 * i + 3], y3);
        }
        float y = ((y0 + y1) + (y2 + y3)) * se_cur;
        se_cur = se_nxt;
        out[(size_t)j * T_LEN + t] =
            LN2 * (__log2f(y) + Eacc - 15.0f * (float)(t + 1));
        float* wr = xbuf[t & 1];
        wr[j] = y;
        __syncthreads();
        if ((t & 1023) == 1023) {
            float v = wr[j];
#pragma unroll
            for (int d = 1; d < 64; d <<= 1) v = fmaxf(v, __shfl_xor(v, d, 64));
            if ((j & 63) == 0) red[j >> 6] = v;
            __syncthreads();
            float m = fmaxf(fmaxf(red[0], red[1]), fmaxf(red[2], red[3]));
            int k = ilogbf(m);
            wr[j] = ldexpf(wr[j], -k);
            Eacc += (float)k;
            __syncthreads();
        }
    }
}

extern "C" void kernel_launch(void* const* d_in, const int* in_sizes, int n_in,
                              void* d_out, int out_size, void* d_ws, size_t ws_size,
                              hipStream_t stream) {
    const float* start = (const float*)d_in[0];
    const float* A     = (const float*)d_in[1];
    const float* E     = (const float*)d_in[2];
    const int*   obs   = (const int*)d_in[3];
    float* out = (float*)d_out;

    char* ws = (char*)d_ws;
    const size_t zb_bytes  = (size_t)T_LEN * NS * sizeof(float);     // 8 MB
    const size_t et_bytes  = (size_t)NF * NS * sizeof(short);        // 16.4 MB
    const size_t asw_bytes = (size_t)16 * 8 * 64 * 8 * sizeof(short);// 128 KB

    float* z     = (float*)ws;
    short* ETb   = (short*)(ws + zb_bytes);
    short* Aswz  = (short*)(ws + zb_bytes + et_bytes);
    float* Pb    = (float*)(ws + zb_bytes + et_bytes + asw_bytes);
    float* Qb    = Pb + C_CH;
    float* Dfull = Qb + C_CH;

    const size_t need = zb_bytes + et_bytes + asw_bytes +
                        (2 * C_CH + T_LEN) * sizeof(float);

    if (ws_size >= need) {
        transpose_E<<<dim3(NF / 64, NS / 64), 256, 0, stream>>>(E, ETb);
        prep_A<<<128, 64, 0, stream>>>(A, Aswz);
        hmm_chains<<<NBLK, 256, 0, stream>>>(start, obs, ETb, Aswz, z, Pb, Qb);
        hmm_stitch<<<1, 256, 0, stream>>>(Pb, Qb, Dfull);
        hmm_finalize<<<dim3(T_LEN / 64, NS / 64), 256, 0, stream>>>(z, Dfull, out);
    } else {
        hmm_forward_seq<<<1, NS, 0, stream>>>(start, A, E, obs, out);
    }
}